// Round 5
// baseline (152.625 us; speedup 1.0000x reference)
//
#include <hip/hip_runtime.h>
#include <hip/hip_bf16.h>
#include <stdint.h>

typedef __hip_bfloat16 bf16;
typedef __attribute__((ext_vector_type(8))) short short8;
typedef __attribute__((ext_vector_type(4))) short short4v;
typedef __attribute__((ext_vector_type(4))) float f32x4;
typedef __attribute__((ext_vector_type(16))) float f32x16;
typedef __attribute__((ext_vector_type(4))) unsigned uint4v;
typedef __attribute__((ext_vector_type(2))) unsigned uint2v;

#define AS1 __attribute__((address_space(1)))
#define AS3 __attribute__((address_space(3)))

static constexpr int SEQ = 2048, DM = 1024, DHD = 64;
static constexpr int MROWS = 2 * SEQ;  // 4096

__device__ __forceinline__ short f2b(float f) {
  __hip_bfloat16 h = __float2bfloat16(f);
  return *reinterpret_cast<short*>(&h);
}

__device__ __forceinline__ unsigned pack2(float lo, float hi) {
  float2 fv; fv.x = lo; fv.y = hi;
  union { __hip_bfloat162 h; unsigned u; } cv;
  cv.h = __float22bfloat162_rn(fv);
  return cv.u;
}

union U8 { uint4v u; short8 s; };

// volatile asm 16B global load with literal byte offset — cannot be sunk/reordered
#define GL16(dst, ptr, off) \
  asm volatile("global_load_dwordx4 %0, %1, off offset:" #off : "=v"(dst) : "v"(ptr))
// counted wait + scheduling fence (rule #18: MFMA can hoist past bare asm waitcnt)
#define WAITV(n) do { asm volatile("s_waitcnt vmcnt(" #n ")"); __builtin_amdgcn_sched_barrier(0); } while (0)

__device__ __forceinline__ float xmax32(float v) {
#if __has_builtin(__builtin_amdgcn_permlane32_swap)
  uint2v r = __builtin_amdgcn_permlane32_swap(__float_as_uint(v), __float_as_uint(v), false, false);
  return fmaxf(__uint_as_float(r[0]), __uint_as_float(r[1]));
#else
  return fmaxf(v, __shfl_xor(v, 32));
#endif
}
__device__ __forceinline__ float xsum32(float v) {
#if __has_builtin(__builtin_amdgcn_permlane32_swap)
  uint2v r = __builtin_amdgcn_permlane32_swap(__float_as_uint(v), __float_as_uint(v), false, false);
  return __uint_as_float(r[0]) + __uint_as_float(r[1]);
#else
  return v + __shfl_xor(v, 32);
#endif
}

// ---------------- prep: x -> bf16, x+pos -> bf16 ----------------
__global__ __launch_bounds__(256) void prep_inputs(const float* __restrict__ x,
                                                   const float* __restrict__ pos,
                                                   bf16* __restrict__ xb,
                                                   bf16* __restrict__ aib) {
  int i = blockIdx.x * 256 + threadIdx.x;
  const int n4 = MROWS * DM / 4;
  if (i >= n4) return;
  f32x4 xv = ((const f32x4*)x)[i];
  f32x4 pv = ((const f32x4*)pos)[i];
  short4v xo, ao;
#pragma unroll
  for (int j = 0; j < 4; ++j) {
    xo[j] = f2b(xv[j]);
    ao[j] = f2b(xv[j] + pv[j]);
  }
  ((short4v*)xb)[i] = xo;
  ((short4v*)aib)[i] = ao;
}

// ---------------- weight transpose: [R][C] f32 -> [C][R] bf16 (per z-slice) --
__global__ __launch_bounds__(256) void transpose_w(const float* __restrict__ in,
                                                   bf16* __restrict__ out, int R, int C) {
  __shared__ float t[64][65];
  int ct = blockIdx.x, rt = blockIdx.y, z = blockIdx.z;
  in += (size_t)z * R * C;
  out += (size_t)z * R * C;
  int c = threadIdx.x & 63, g = threadIdx.x >> 6;
#pragma unroll
  for (int j = 0; j < 16; ++j) {
    int r = g * 16 + j;
    t[r][c] = in[(size_t)(rt * 64 + r) * C + (ct * 64 + c)];
  }
  __syncthreads();
#pragma unroll
  for (int j = 0; j < 16; ++j) {
    int rr = g * 16 + j;
    out[(size_t)(ct * 64 + rr) * R + (rt * 64 + c)] = __float2bfloat16(t[c][rr]);
  }
}

// ---------------- 128x128 GEMM body (A[M][1024] bf16, Bt[N][1024] bf16) -----
template <int MODE, typename OutT>
__device__ __forceinline__ void gemm128_body(const bf16* __restrict__ A,
                                             const bf16* __restrict__ Bt,
                                             const float* __restrict__ bias,
                                             OutT* __restrict__ C, int mt, int nt,
                                             float scale) {
  __shared__ alignas(16) bf16 Al[128 * 32];
  __shared__ alignas(16) bf16 Bl[128 * 32];
  const int lane = threadIdx.x & 63, wv = threadIdx.x >> 6;
  const int wr = wv >> 1, wc = wv & 1;
  const bf16* Ab = A + (size_t)mt * 128 * DM;
  const bf16* Bb = Bt + (size_t)nt * 128 * DM;

  f32x4 acc[4][4];
#pragma unroll
  for (int i = 0; i < 4; ++i)
#pragma unroll
    for (int j = 0; j < 4; ++j) acc[i][j] = (f32x4){0.f, 0.f, 0.f, 0.f};

  for (int kt = 0; kt < DM / 32; ++kt) {
    int k0 = kt * 32;
#pragma unroll
    for (int c = 0; c < 2; ++c) {
      int li0 = wv * 64 + c * 256;
      int li = li0 + lane;
      int row = li >> 2, sl = li & 3;
      int gs = sl ^ ((row >> 1) & 3);
      __builtin_amdgcn_global_load_lds((const AS1 void*)(Ab + (size_t)row * DM + k0 + gs * 8),
                                       (AS3 void*)(&Al[li0 * 8]), 16, 0, 0);
    }
#pragma unroll
    for (int c = 0; c < 2; ++c) {
      int li0 = wv * 64 + c * 256;
      int li = li0 + lane;
      int row = li >> 2, sl = li & 3;
      int gs = sl ^ ((row >> 1) & 3);
      __builtin_amdgcn_global_load_lds((const AS1 void*)(Bb + (size_t)row * DM + k0 + gs * 8),
                                       (AS3 void*)(&Bl[li0 * 8]), 16, 0, 0);
    }
    __syncthreads();

    short8 af[4], bfr[4];
    const int kb = lane >> 4;
#pragma unroll
    for (int mi = 0; mi < 4; ++mi) {
      int r = wr * 64 + mi * 16 + (lane & 15);
      af[mi] = *(const short8*)(&Al[r * 32 + ((kb ^ ((r >> 1) & 3)) << 3)]);
    }
#pragma unroll
    for (int ni = 0; ni < 4; ++ni) {
      int r = wc * 64 + ni * 16 + (lane & 15);
      bfr[ni] = *(const short8*)(&Bl[r * 32 + ((kb ^ ((r >> 1) & 3)) << 3)]);
    }
#pragma unroll
    for (int mi = 0; mi < 4; ++mi)
#pragma unroll
      for (int ni = 0; ni < 4; ++ni)
        acc[mi][ni] = __builtin_amdgcn_mfma_f32_16x16x32_bf16(af[mi], bfr[ni], acc[mi][ni], 0, 0, 0);
    __syncthreads();
  }

#pragma unroll
  for (int mi = 0; mi < 4; ++mi) {
#pragma unroll
    for (int ni = 0; ni < 4; ++ni) {
      int col = nt * 128 + wc * 64 + ni * 16 + (lane & 15);
      float bv = bias[col];
      if constexpr (MODE == 2) {
        int row0 = mt * 128 + wr * 64 + mi * 16 + (lane >> 4) * 4;
        int bb = row0 >> 11, s = row0 & 2047;
        int h = col >> 6, d = col & 63;
        short4v o;
#pragma unroll
        for (int j = 0; j < 4; ++j) o[j] = f2b(acc[mi][ni][j] + bv);
        *(short4v*)((bf16*)C + ((size_t)((bb * 16 + h) * 64 + d)) * SEQ + s) = o;
      } else {
#pragma unroll
        for (int j = 0; j < 4; ++j) {
          int row = mt * 128 + wr * 64 + mi * 16 + (lane >> 4) * 4 + j;
          float v = (acc[mi][ni][j] + bv) * scale;
          if constexpr (MODE == 0) {
            C[(size_t)row * DM + col] = __float2bfloat16(v);
          } else {
            C[(size_t)row * DM + col] = v;
          }
        }
      }
    }
  }
}

// Q prescale: (1/sqrt(64)) * log2(e) so attention uses exp2
static constexpr float QSCALE = 0.125f * 1.4426950408889634f;

__global__ __launch_bounds__(256) void qkv_gemm(const bf16* __restrict__ aib,
                                                const bf16* __restrict__ xb,
                                                const bf16* __restrict__ wqt,
                                                const bf16* __restrict__ wkt,
                                                const bf16* __restrict__ wvt,
                                                const float* __restrict__ bq,
                                                const float* __restrict__ bk,
                                                const float* __restrict__ bv,
                                                bf16* __restrict__ Q, bf16* __restrict__ K,
                                                bf16* __restrict__ Vt) {
  int mt = blockIdx.x & 31;
  int nt = (blockIdx.x >> 5) & 7;
  int mat = blockIdx.x >> 8;
  if (mat == 0) {
    gemm128_body<0>(aib, wqt, bq, Q, mt, nt, QSCALE);
  } else if (mat == 1) {
    gemm128_body<0>(aib, wkt, bk, K, mt, nt, 1.0f);
  } else {
    gemm128_body<2>(xb, wvt, bv, Vt, mt, nt, 1.0f);
  }
}

__global__ __launch_bounds__(256) void o_gemm(const bf16* __restrict__ Z,
                                              const bf16* __restrict__ wot,
                                              const float* __restrict__ bo,
                                              float* __restrict__ out) {
  int mt = blockIdx.x & 31;
  int nt = blockIdx.x >> 5;
  gemm128_body<1>(Z, wot, bo, out, mt, nt, 1.0f);
}

// ---------------- flash attention: swapped-QK^T, 1 wave / 32 q-rows ----------
// All Q/K/V loads are volatile-asm global_load_dwordx4 with counted vmcnt
// waits: V(t) issued at tile top (consumed at PV, covered by QK+softmax);
// K(t+1) issued after QK (covered by softmax+PV+next V-issue). Never drain
// vmcnt to 0 except before the final PV.
__global__ __launch_bounds__(64, 2) void flash_attn(const bf16* __restrict__ Qb,
                                                    const bf16* __restrict__ Kb,
                                                    const bf16* __restrict__ Vt,
                                                    bf16* __restrict__ Zb) {
  __shared__ unsigned Zl[32 * 32];  // 4KB, final ZT->Z transpose

  const int lane = threadIdx.x;
  const int qln = lane & 31;
  const int hi8 = (lane >> 5) * 8;
  const bool hib = lane >= 32;
  const int bh = blockIdx.x & 31;           // bh%8 -> XCD affinity
  const int wq = 63 - (blockIdx.x >> 5);    // heavy blocks dispatch first
  const int bb = bh >> 4, h = bh & 15;
  const size_t base = ((size_t)bb * SEQ) * DM + h * DHD;
  const size_t vbase = (size_t)bh * DHD * SEQ;
  const int q0 = wq * 32;
  const int ntiles = wq / 2 + 1;

  // walking per-lane pointers (advanced with uniform strides per tile)
  const bf16* kp0 = Kb + base + (size_t)qln * DM + hi8;
  const bf16* kp1 = Kb + base + (size_t)(32 + qln) * DM + hi8;
  const bf16* vp0 = Vt + vbase + (size_t)qln * SEQ + hi8;
  const bf16* vp1 = Vt + vbase + (size_t)(32 + qln) * SEQ + hi8;
  const bf16* qp  = Qb + base + (size_t)(q0 + qln) * DM + hi8;

  short8 qf[4];
  short8 kfA[2][4], kfB[2][4];
  // prologue: Q (4 loads) then K(0) (8 loads)
  GL16(qf[0], qp, 0);  GL16(qf[1], qp, 32);  GL16(qf[2], qp, 64);  GL16(qf[3], qp, 96);
  GL16(kfA[0][0], kp0, 0); GL16(kfA[0][1], kp0, 32); GL16(kfA[0][2], kp0, 64); GL16(kfA[0][3], kp0, 96);
  GL16(kfA[1][0], kp1, 0); GL16(kfA[1][1], kp1, 32); GL16(kfA[1][2], kp1, 64); GL16(kfA[1][3], kp1, 96);
  kp0 += 64 * DM; kp1 += 64 * DM;

  f32x16 zacc[2];
#pragma unroll
  for (int i = 0; i < 16; ++i) { zacc[0][i] = 0.f; zacc[1][i] = 0.f; }
  float mrun = -1e30f, lrun = 0.f;

  auto computeT = [&](short8(&kf)[2][4], short8(&kfn)[2][4], int t) {
    const int kv0 = t * 64;
    const bool pref = (t + 1 < ntiles);

    // issue V(t) — consumed at PV below (covered by QK + K-issue + softmax)
    short8 vf[2][4];
    GL16(vf[0][0], vp0, 0); GL16(vf[0][1], vp0, 32); GL16(vf[0][2], vp0, 64); GL16(vf[0][3], vp0, 96);
    GL16(vf[1][0], vp1, 0); GL16(vf[1][1], vp1, 32); GL16(vf[1][2], vp1, 64); GL16(vf[1][3], vp1, 96);
    vp0 += 64; vp1 += 64;

    WAITV(8);  // K(t) (and Q on t=0) complete; V(t)'s 8 loads stay in flight

    // S^T[kv][q]
    f32x16 s[2];
#pragma unroll
    for (int i = 0; i < 16; ++i) { s[0][i] = 0.f; s[1][i] = 0.f; }
#pragma unroll
    for (int kc = 0; kc < 4; ++kc) {
      s[0] = __builtin_amdgcn_mfma_f32_32x32x16_bf16(kf[0][kc], qf[kc], s[0], 0, 0, 0);
      s[1] = __builtin_amdgcn_mfma_f32_32x32x16_bf16(kf[1][kc], qf[kc], s[1], 0, 0, 0);
    }

    if (pref) {  // issue K(t+1)
      GL16(kfn[0][0], kp0, 0); GL16(kfn[0][1], kp0, 32); GL16(kfn[0][2], kp0, 64); GL16(kfn[0][3], kp0, 96);
      GL16(kfn[1][0], kp1, 0); GL16(kfn[1][1], kp1, 32); GL16(kfn[1][2], kp1, 64); GL16(kfn[1][3], kp1, 96);
      kp0 += 64 * DM; kp1 += 64 * DM;
    }

    if (t == ntiles - 1) {  // causal mask, only diagonal tile
      const int qg = q0 + qln;
#pragma unroll
      for (int ni = 0; ni < 2; ++ni)
#pragma unroll
        for (int rr = 0; rr < 16; ++rr) {
          int kv = kv0 + 32 * ni + (rr & 3) + 8 * (rr >> 2) + (hib ? 4 : 0);
          if (kv > qg) s[ni][rr] = -1e30f;
        }
    }

    // row max: in-register tree + cross-half swap
    float t8[8];
#pragma unroll
    for (int i = 0; i < 8; ++i)
      t8[i] = fmaxf(fmaxf(s[0][i], s[0][i + 8]), fmaxf(s[1][i], s[1][i + 8]));
    float tm = fmaxf(fmaxf(fmaxf(t8[0], t8[1]), fmaxf(t8[2], t8[3])),
                     fmaxf(fmaxf(t8[4], t8[5]), fmaxf(t8[6], t8[7])));
    tm = xmax32(tm);

    // defer-max: rescale only if the running max grew (exact)
    if (__ballot(tm > mrun)) {
      float mn = fmaxf(mrun, tm);
      float al = exp2f(mrun - mn);
      mrun = mn;
      lrun *= al;
#pragma unroll
      for (int i = 0; i < 16; ++i) { zacc[0][i] *= al; zacc[1][i] *= al; }
    }

    float pacc[4] = {0.f, 0.f, 0.f, 0.f};
#pragma unroll
    for (int ni = 0; ni < 2; ++ni)
#pragma unroll
      for (int rr = 0; rr < 16; ++rr) {
        float p = exp2f(s[ni][rr] - mrun);
        s[ni][rr] = p;
        pacc[rr & 3] += p;
      }
    lrun += xsum32((pacc[0] + pacc[1]) + (pacc[2] + pacc[3]));

    // P -> bf16 B-fragments: pack pairs, permlane32_swap fills both halves
    unsigned su32[2][8];
#pragma unroll
    for (int ni = 0; ni < 2; ++ni)
#pragma unroll
      for (int tt = 0; tt < 8; ++tt)
        su32[ni][tt] = pack2(s[ni][2 * tt], s[ni][2 * tt + 1]);

    short8 pa[4];
#if __has_builtin(__builtin_amdgcn_permlane32_swap)
#pragma unroll
    for (int c = 0; c < 4; ++c) {
      int ni = c >> 1, b4 = 4 * (c & 1);
      uint2v r0 = __builtin_amdgcn_permlane32_swap(su32[ni][b4 + 0], su32[ni][b4 + 2], false, false);
      uint2v r1 = __builtin_amdgcn_permlane32_swap(su32[ni][b4 + 1], su32[ni][b4 + 3], false, false);
      U8 w;
      w.u[0] = r0[0]; w.u[1] = r1[0]; w.u[2] = r0[1]; w.u[3] = r1[1];
      pa[c] = w.s;
    }
#else
    unsigned X[2][8];
#pragma unroll
    for (int ni = 0; ni < 2; ++ni)
#pragma unroll
      for (int tt = 0; tt < 8; ++tt)
        X[ni][tt] = (unsigned)__shfl_xor((int)su32[ni][tt], 32);
#pragma unroll
    for (int c = 0; c < 4; ++c) {
      int ni = c >> 1, b4 = 4 * (c & 1);
      U8 w;
      w.u[0] = hib ? X[ni][b4 + 2] : su32[ni][b4 + 0];
      w.u[1] = hib ? X[ni][b4 + 3] : su32[ni][b4 + 1];
      w.u[2] = hib ? su32[ni][b4 + 2] : X[ni][b4 + 0];
      w.u[3] = hib ? su32[ni][b4 + 3] : X[ni][b4 + 1];
      pa[c] = w.s;
    }
#endif

    if (pref) { WAITV(8); } else { WAITV(0); }  // V(t) done; K(t+1) stays in flight

    // Z^T += V^T * P
#pragma unroll
    for (int c = 0; c < 4; ++c) {
      zacc[0] = __builtin_amdgcn_mfma_f32_32x32x16_bf16(vf[0][c], pa[c], zacc[0], 0, 0, 0);
      zacc[1] = __builtin_amdgcn_mfma_f32_32x32x16_bf16(vf[1][c], pa[c], zacc[1], 0, 0, 0);
    }
  };

  int t = 0;
  while (true) {
    computeT(kfA, kfB, t);
    if (++t >= ntiles) break;
    computeT(kfB, kfA, t);
    if (++t >= ntiles) break;
  }

  // normalize + transpose Z^T -> Z via swizzled LDS, coalesced store
  const float rl = 1.0f / lrun;
  const int W8[8] = {0, 1, 4, 5, 8, 9, 12, 13};
#pragma unroll
  for (int dj = 0; dj < 2; ++dj)
#pragma unroll
    for (int tt = 0; tt < 8; ++tt) {
      unsigned v = pack2(zacc[dj][2 * tt] * rl, zacc[dj][2 * tt + 1] * rl);
      int x = 16 * dj + (hib ? 2 : 0) + W8[tt];
      Zl[qln * 32 + (((x >> 2) ^ (qln & 7)) << 2) + (x & 3)] = v;
    }
  asm volatile("s_waitcnt lgkmcnt(0)" ::: "memory");
  __builtin_amdgcn_sched_barrier(0);
  int q2 = lane >> 1, hf = lane & 1;
#pragma unroll
  for (int u = 0; u < 4; ++u) {
    int sl = (hf * 4 + u) ^ (q2 & 7);
    U8 w;
    w.u = *(const uint4v*)&Zl[q2 * 32 + sl * 4];
    *(short8*)(Zb + base + (size_t)(q0 + q2) * DM + hf * 32 + u * 8) = w.s;
  }
}

extern "C" void kernel_launch(void* const* d_in, const int* in_sizes, int n_in,
                              void* d_out, int out_size, void* d_ws, size_t ws_size,
                              hipStream_t stream) {
  (void)in_sizes; (void)n_in; (void)out_size; (void)ws_size;
  const float* x = (const float*)d_in[0];
  const float* pos = (const float*)d_in[1];
  const float* WQ = (const float*)d_in[2];
  const float* bQ = (const float*)d_in[3];
  const float* WK = (const float*)d_in[4];
  const float* bK = (const float*)d_in[5];
  const float* WV = (const float*)d_in[6];
  const float* bV = (const float*)d_in[7];
  const float* WO = (const float*)d_in[8];
  const float* bO = (const float*)d_in[9];
  float* out = (float*)d_out;

  bf16* ws = (bf16*)d_ws;
  size_t off = 0;
  bf16* aib = ws + off; off += (size_t)MROWS * DM;
  bf16* xb  = ws + off; off += (size_t)MROWS * DM;
  bf16* wqt = ws + off; off += (size_t)DM * DM;
  bf16* wkt = ws + off; off += (size_t)DM * DM;
  bf16* wvt = ws + off; off += (size_t)DM * DM;
  bf16* wot = ws + off; off += (size_t)DM * DM;
  bf16* Qb  = ws + off; off += (size_t)MROWS * DM;
  bf16* Kb  = ws + off; off += (size_t)MROWS * DM;
  bf16* Vtb = ws + off; off += (size_t)MROWS * DM;  // [bh][d][s]
  bf16* Zb  = ws + off; off += (size_t)MROWS * DM;

  prep_inputs<<<(MROWS * DM / 4 + 255) / 256, 256, 0, stream>>>(x, pos, xb, aib);
  dim3 gq(1, 16, 16);
  transpose_w<<<gq, 256, 0, stream>>>(WQ, wqt, 1024, 64);
  transpose_w<<<gq, 256, 0, stream>>>(WK, wkt, 1024, 64);
  transpose_w<<<gq, 256, 0, stream>>>(WV, wvt, 1024, 64);
  dim3 go(16, 16, 1);
  transpose_w<<<go, 256, 0, stream>>>(WO, wot, 1024, 1024);
  qkv_gemm<<<768, 256, 0, stream>>>(aib, xb, wqt, wkt, wvt, bQ, bK, bV, Qb, Kb, Vtb);
  flash_attn<<<2048, 64, 0, stream>>>(Qb, Kb, Vtb, Zb);
  o_gemm<<<256, 256, 0, stream>>>(Zb, wot, bO, out);
}

// Round 6
// 138.726 us; speedup vs baseline: 1.1002x; 1.1002x over previous
//
#include <hip/hip_runtime.h>
#include <hip/hip_bf16.h>
#include <stdint.h>

typedef __hip_bfloat16 bf16;
typedef __attribute__((ext_vector_type(8))) short short8;
typedef __attribute__((ext_vector_type(4))) short short4v;
typedef __attribute__((ext_vector_type(4))) float f32x4;
typedef __attribute__((ext_vector_type(16))) float f32x16;
typedef __attribute__((ext_vector_type(4))) unsigned uint4v;
typedef __attribute__((ext_vector_type(2))) unsigned uint2v;

#define AS1 __attribute__((address_space(1)))
#define AS3 __attribute__((address_space(3)))

static constexpr int SEQ = 2048, DM = 1024, DHD = 64;
static constexpr int MROWS = 2 * SEQ;  // 4096

__device__ __forceinline__ short f2b(float f) {
  __hip_bfloat16 h = __float2bfloat16(f);
  return *reinterpret_cast<short*>(&h);
}

__device__ __forceinline__ unsigned pack2(float lo, float hi) {
  float2 fv; fv.x = lo; fv.y = hi;
  union { __hip_bfloat162 h; unsigned u; } cv;
  cv.h = __float22bfloat162_rn(fv);
  return cv.u;
}

union U8 { uint4v u; short8 s; };

// volatile asm 16B global load with literal byte offset — cannot be sunk/reordered
#define GL16(dst, ptr, off) \
  asm volatile("global_load_dwordx4 %0, %1, off offset:" #off : "=v"(dst) : "v"(ptr))
// counted wait + scheduling fence (rule #18)
#define WAITV(n) do { asm volatile("s_waitcnt vmcnt(" #n ")"); __builtin_amdgcn_sched_barrier(0); } while (0)

__device__ __forceinline__ float xmax32(float v) {
#if __has_builtin(__builtin_amdgcn_permlane32_swap)
  uint2v r = __builtin_amdgcn_permlane32_swap(__float_as_uint(v), __float_as_uint(v), false, false);
  return fmaxf(__uint_as_float(r[0]), __uint_as_float(r[1]));
#else
  return fmaxf(v, __shfl_xor(v, 32));
#endif
}
__device__ __forceinline__ float xsum32(float v) {
#if __has_builtin(__builtin_amdgcn_permlane32_swap)
  uint2v r = __builtin_amdgcn_permlane32_swap(__float_as_uint(v), __float_as_uint(v), false, false);
  return __uint_as_float(r[0]) + __uint_as_float(r[1]);
#else
  return v + __shfl_xor(v, 32);
#endif
}

// ---------------- prep: x -> bf16, x+pos -> bf16 ----------------
__global__ __launch_bounds__(256) void prep_inputs(const float* __restrict__ x,
                                                   const float* __restrict__ pos,
                                                   bf16* __restrict__ xb,
                                                   bf16* __restrict__ aib) {
  int i = blockIdx.x * 256 + threadIdx.x;
  const int n4 = MROWS * DM / 4;
  if (i >= n4) return;
  f32x4 xv = ((const f32x4*)x)[i];
  f32x4 pv = ((const f32x4*)pos)[i];
  short4v xo, ao;
#pragma unroll
  for (int j = 0; j < 4; ++j) {
    xo[j] = f2b(xv[j]);
    ao[j] = f2b(xv[j] + pv[j]);
  }
  ((short4v*)xb)[i] = xo;
  ((short4v*)aib)[i] = ao;
}

// ---------------- weight transpose: [R][C] f32 -> [C][R] bf16 (per z-slice) --
__global__ __launch_bounds__(256) void transpose_w(const float* __restrict__ in,
                                                   bf16* __restrict__ out, int R, int C) {
  __shared__ float t[64][65];
  int ct = blockIdx.x, rt = blockIdx.y, z = blockIdx.z;
  in += (size_t)z * R * C;
  out += (size_t)z * R * C;
  int c = threadIdx.x & 63, g = threadIdx.x >> 6;
#pragma unroll
  for (int j = 0; j < 16; ++j) {
    int r = g * 16 + j;
    t[r][c] = in[(size_t)(rt * 64 + r) * C + (ct * 64 + c)];
  }
  __syncthreads();
#pragma unroll
  for (int j = 0; j < 16; ++j) {
    int rr = g * 16 + j;
    out[(size_t)(ct * 64 + rr) * R + (rt * 64 + c)] = __float2bfloat16(t[c][rr]);
  }
}

// ---------------- 128x128 GEMM body (A[M][1024] bf16, Bt[N][1024] bf16) -----
template <int MODE, typename OutT>
__device__ __forceinline__ void gemm128_body(const bf16* __restrict__ A,
                                             const bf16* __restrict__ Bt,
                                             const float* __restrict__ bias,
                                             OutT* __restrict__ C, int mt, int nt,
                                             float scale) {
  __shared__ alignas(16) bf16 Al[128 * 32];
  __shared__ alignas(16) bf16 Bl[128 * 32];
  const int lane = threadIdx.x & 63, wv = threadIdx.x >> 6;
  const int wr = wv >> 1, wc = wv & 1;
  const bf16* Ab = A + (size_t)mt * 128 * DM;
  const bf16* Bb = Bt + (size_t)nt * 128 * DM;

  f32x4 acc[4][4];
#pragma unroll
  for (int i = 0; i < 4; ++i)
#pragma unroll
    for (int j = 0; j < 4; ++j) acc[i][j] = (f32x4){0.f, 0.f, 0.f, 0.f};

  for (int kt = 0; kt < DM / 32; ++kt) {
    int k0 = kt * 32;
#pragma unroll
    for (int c = 0; c < 2; ++c) {
      int li0 = wv * 64 + c * 256;
      int li = li0 + lane;
      int row = li >> 2, sl = li & 3;
      int gs = sl ^ ((row >> 1) & 3);
      __builtin_amdgcn_global_load_lds((const AS1 void*)(Ab + (size_t)row * DM + k0 + gs * 8),
                                       (AS3 void*)(&Al[li0 * 8]), 16, 0, 0);
    }
#pragma unroll
    for (int c = 0; c < 2; ++c) {
      int li0 = wv * 64 + c * 256;
      int li = li0 + lane;
      int row = li >> 2, sl = li & 3;
      int gs = sl ^ ((row >> 1) & 3);
      __builtin_amdgcn_global_load_lds((const AS1 void*)(Bb + (size_t)row * DM + k0 + gs * 8),
                                       (AS3 void*)(&Bl[li0 * 8]), 16, 0, 0);
    }
    __syncthreads();

    short8 af[4], bfr[4];
    const int kb = lane >> 4;
#pragma unroll
    for (int mi = 0; mi < 4; ++mi) {
      int r = wr * 64 + mi * 16 + (lane & 15);
      af[mi] = *(const short8*)(&Al[r * 32 + ((kb ^ ((r >> 1) & 3)) << 3)]);
    }
#pragma unroll
    for (int ni = 0; ni < 4; ++ni) {
      int r = wc * 64 + ni * 16 + (lane & 15);
      bfr[ni] = *(const short8*)(&Bl[r * 32 + ((kb ^ ((r >> 1) & 3)) << 3)]);
    }
#pragma unroll
    for (int mi = 0; mi < 4; ++mi)
#pragma unroll
      for (int ni = 0; ni < 4; ++ni)
        acc[mi][ni] = __builtin_amdgcn_mfma_f32_16x16x32_bf16(af[mi], bfr[ni], acc[mi][ni], 0, 0, 0);
    __syncthreads();
  }

#pragma unroll
  for (int mi = 0; mi < 4; ++mi) {
#pragma unroll
    for (int ni = 0; ni < 4; ++ni) {
      int col = nt * 128 + wc * 64 + ni * 16 + (lane & 15);
      float bv = bias[col];
      if constexpr (MODE == 2) {
        int row0 = mt * 128 + wr * 64 + mi * 16 + (lane >> 4) * 4;
        int bb = row0 >> 11, s = row0 & 2047;
        int h = col >> 6, d = col & 63;
        short4v o;
#pragma unroll
        for (int j = 0; j < 4; ++j) o[j] = f2b(acc[mi][ni][j] + bv);
        *(short4v*)((bf16*)C + ((size_t)((bb * 16 + h) * 64 + d)) * SEQ + s) = o;
      } else {
#pragma unroll
        for (int j = 0; j < 4; ++j) {
          int row = mt * 128 + wr * 64 + mi * 16 + (lane >> 4) * 4 + j;
          float v = (acc[mi][ni][j] + bv) * scale;
          if constexpr (MODE == 0) {
            C[(size_t)row * DM + col] = __float2bfloat16(v);
          } else {
            C[(size_t)row * DM + col] = v;
          }
        }
      }
    }
  }
}

// Q prescale: (1/sqrt(64)) * log2(e) so attention uses exp2
static constexpr float QSCALE = 0.125f * 1.4426950408889634f;

__global__ __launch_bounds__(256) void qkv_gemm(const bf16* __restrict__ aib,
                                                const bf16* __restrict__ xb,
                                                const bf16* __restrict__ wqt,
                                                const bf16* __restrict__ wkt,
                                                const bf16* __restrict__ wvt,
                                                const float* __restrict__ bq,
                                                const float* __restrict__ bk,
                                                const float* __restrict__ bv,
                                                bf16* __restrict__ Q, bf16* __restrict__ K,
                                                bf16* __restrict__ Vt) {
  int mt = blockIdx.x & 31;
  int nt = (blockIdx.x >> 5) & 7;
  int mat = blockIdx.x >> 8;
  if (mat == 0) {
    gemm128_body<0>(aib, wqt, bq, Q, mt, nt, QSCALE);
  } else if (mat == 1) {
    gemm128_body<0>(aib, wkt, bk, K, mt, nt, 1.0f);
  } else {
    gemm128_body<2>(xb, wvt, bv, Vt, mt, nt, 1.0f);
  }
}

__global__ __launch_bounds__(256) void o_gemm(const bf16* __restrict__ Z,
                                              const bf16* __restrict__ wot,
                                              const float* __restrict__ bo,
                                              float* __restrict__ out) {
  int mt = blockIdx.x & 31;
  int nt = blockIdx.x >> 5;
  gemm128_body<1>(Z, wot, bo, out, mt, nt, 1.0f);
}

// ---------------- repack K/V into MFMA fragment-major layout ----------------
// FK[bh][g][kc] is a 1KB block: byte lane*16 holds K[g*32+(lane&31)][kc*16+(lane>=32)*8 ..+8]
__global__ __launch_bounds__(256) void repack_k(const bf16* __restrict__ K,
                                                bf16* __restrict__ FK) {
  int bh = blockIdx.x, g = blockIdx.y;
  int bb = bh >> 4, h = bh & 15;
  int t = threadIdx.x, r = t >> 3, sl = t & 7, kc = sl >> 1, hi = sl & 1;
  short8 v = *(const short8*)(K + (size_t)(bb * SEQ + g * 32 + r) * DM + h * 64 + kc * 16 + hi * 8);
  *(short8*)(FK + (size_t)bh * 131072 + (g * 4 + kc) * 512 + (r + 32 * hi) * 8) = v;
}

// FV[bh][dj][ks] 1KB block: byte lane*16 holds Vt[dj*32+(lane&31)][ks*16+(lane>=32)*8 ..+8]
__global__ __launch_bounds__(256) void repack_v(const bf16* __restrict__ Vt,
                                                bf16* __restrict__ FV) {
  int bh = blockIdx.x, dj = blockIdx.y, sc = blockIdx.z;
  int t = threadIdx.x, r = t >> 3, sl = t & 7, hi = sl & 1;
#pragma unroll
  for (int cc = 0; cc < 4; ++cc) {
    int col = sc * 256 + cc * 64 + sl * 8;
    int ks = col >> 4;
    short8 v = *(const short8*)(Vt + (size_t)bh * 131072 + (size_t)(dj * 32 + r) * SEQ + col);
    *(short8*)(FV + (size_t)bh * 131072 + (size_t)dj * 65536 + (size_t)ks * 512 + (r + 32 * hi) * 8) = v;
  }
}

// ---------------- flash attention: swapped-QK^T, 1 wave / 32 q-rows ----------
// K/V read from fragment-major FK/FV: every load is a fully-coalesced 1KB
// global_load_dwordx4 (lane*16B contiguous). V(t) issued at tile top; K(t+1)
// after QK; counted vmcnt keeps 8 loads in flight across phases.
__global__ __launch_bounds__(64, 2) void flash_attn(const bf16* __restrict__ Qb,
                                                    const bf16* __restrict__ FK,
                                                    const bf16* __restrict__ FV,
                                                    bf16* __restrict__ Zb) {
  __shared__ unsigned Zl[32 * 32];  // 4KB, final ZT->Z transpose

  const int lane = threadIdx.x;
  const int qln = lane & 31;
  const int hi8 = (lane >> 5) * 8;
  const bool hib = lane >= 32;
  const int bh = blockIdx.x & 31;           // bh%8 -> XCD affinity
  const int wq = 63 - (blockIdx.x >> 5);    // heavy blocks dispatch first
  const int bb = bh >> 4, h = bh & 15;
  const size_t base = ((size_t)bb * SEQ) * DM + h * DHD;
  const int q0 = wq * 32;
  const int ntiles = wq / 2 + 1;

  // walking fragment pointers (per-lane 16B slot; uniform tile advance)
  const bf16* qp  = Qb + base + (size_t)(q0 + qln) * DM + hi8;
  const bf16* kpt = FK + (size_t)bh * 131072 + lane * 8;
  const bf16* vp0 = FV + (size_t)bh * 131072 + lane * 8;
  const bf16* vp1 = vp0 + 65536;

  short8 qf[4];
  short8 kfA[2][4], kfB[2][4];
  // prologue: Q (4 loads, once) then K(0) (8 coalesced loads)
  GL16(qf[0], qp, 0);  GL16(qf[1], qp, 32);  GL16(qf[2], qp, 64);  GL16(qf[3], qp, 96);
  {
    const bf16* k1 = kpt + 2048;
    GL16(kfA[0][0], kpt, 0); GL16(kfA[0][1], kpt, 1024); GL16(kfA[0][2], kpt, 2048); GL16(kfA[0][3], kpt, 3072);
    GL16(kfA[1][0], k1, 0);  GL16(kfA[1][1], k1, 1024);  GL16(kfA[1][2], k1, 2048);  GL16(kfA[1][3], k1, 3072);
    kpt += 4096;
  }

  f32x16 zacc[2];
#pragma unroll
  for (int i = 0; i < 16; ++i) { zacc[0][i] = 0.f; zacc[1][i] = 0.f; }
  float mrun = -1e30f, lrun = 0.f;

  auto computeT = [&](short8(&kf)[2][4], short8(&kfn)[2][4], int t) {
    const int kv0 = t * 64;
    const bool pref = (t + 1 < ntiles);

    // issue V(t) — consumed at PV below
    short8 vf[2][4];
    GL16(vf[0][0], vp0, 0); GL16(vf[0][1], vp0, 1024); GL16(vf[0][2], vp0, 2048); GL16(vf[0][3], vp0, 3072);
    GL16(vf[1][0], vp1, 0); GL16(vf[1][1], vp1, 1024); GL16(vf[1][2], vp1, 2048); GL16(vf[1][3], vp1, 3072);
    vp0 += 2048; vp1 += 2048;

    WAITV(8);  // K(t) (and Q on t=0) complete; V(t)'s 8 loads stay in flight

    // S^T[kv][q]
    f32x16 s[2];
#pragma unroll
    for (int i = 0; i < 16; ++i) { s[0][i] = 0.f; s[1][i] = 0.f; }
#pragma unroll
    for (int kc = 0; kc < 4; ++kc) {
      s[0] = __builtin_amdgcn_mfma_f32_32x32x16_bf16(kf[0][kc], qf[kc], s[0], 0, 0, 0);
      s[1] = __builtin_amdgcn_mfma_f32_32x32x16_bf16(kf[1][kc], qf[kc], s[1], 0, 0, 0);
    }

    if (pref) {  // issue K(t+1)
      const bf16* k1 = kpt + 2048;
      GL16(kfn[0][0], kpt, 0); GL16(kfn[0][1], kpt, 1024); GL16(kfn[0][2], kpt, 2048); GL16(kfn[0][3], kpt, 3072);
      GL16(kfn[1][0], k1, 0);  GL16(kfn[1][1], k1, 1024);  GL16(kfn[1][2], k1, 2048);  GL16(kfn[1][3], k1, 3072);
      kpt += 4096;
    }

    if (t == ntiles - 1) {  // causal mask, only diagonal tile
      const int qg = q0 + qln;
#pragma unroll
      for (int ni = 0; ni < 2; ++ni)
#pragma unroll
        for (int rr = 0; rr < 16; ++rr) {
          int kv = kv0 + 32 * ni + (rr & 3) + 8 * (rr >> 2) + (hib ? 4 : 0);
          if (kv > qg) s[ni][rr] = -1e30f;
        }
    }

    // row max: in-register tree + cross-half swap
    float t8[8];
#pragma unroll
    for (int i = 0; i < 8; ++i)
      t8[i] = fmaxf(fmaxf(s[0][i], s[0][i + 8]), fmaxf(s[1][i], s[1][i + 8]));
    float tm = fmaxf(fmaxf(fmaxf(t8[0], t8[1]), fmaxf(t8[2], t8[3])),
                     fmaxf(fmaxf(t8[4], t8[5]), fmaxf(t8[6], t8[7])));
    tm = xmax32(tm);

    // defer-max: rescale only if the running max grew (exact)
    if (__ballot(tm > mrun)) {
      float mn = fmaxf(mrun, tm);
      float al = exp2f(mrun - mn);
      mrun = mn;
      lrun *= al;
#pragma unroll
      for (int i = 0; i < 16; ++i) { zacc[0][i] *= al; zacc[1][i] *= al; }
    }

    float pacc[4] = {0.f, 0.f, 0.f, 0.f};
#pragma unroll
    for (int ni = 0; ni < 2; ++ni)
#pragma unroll
      for (int rr = 0; rr < 16; ++rr) {
        float p = exp2f(s[ni][rr] - mrun);
        s[ni][rr] = p;
        pacc[rr & 3] += p;
      }
    lrun += xsum32((pacc[0] + pacc[1]) + (pacc[2] + pacc[3]));

    // P -> bf16 B-fragments: pack pairs, permlane32_swap fills both halves
    unsigned su32[2][8];
#pragma unroll
    for (int ni = 0; ni < 2; ++ni)
#pragma unroll
      for (int tt = 0; tt < 8; ++tt)
        su32[ni][tt] = pack2(s[ni][2 * tt], s[ni][2 * tt + 1]);

    short8 pa[4];
#if __has_builtin(__builtin_amdgcn_permlane32_swap)
#pragma unroll
    for (int c = 0; c < 4; ++c) {
      int ni = c >> 1, b4 = 4 * (c & 1);
      uint2v r0 = __builtin_amdgcn_permlane32_swap(su32[ni][b4 + 0], su32[ni][b4 + 2], false, false);
      uint2v r1 = __builtin_amdgcn_permlane32_swap(su32[ni][b4 + 1], su32[ni][b4 + 3], false, false);
      U8 w;
      w.u[0] = r0[0]; w.u[1] = r1[0]; w.u[2] = r0[1]; w.u[3] = r1[1];
      pa[c] = w.s;
    }
#else
    unsigned X[2][8];
#pragma unroll
    for (int ni = 0; ni < 2; ++ni)
#pragma unroll
      for (int tt = 0; tt < 8; ++tt)
        X[ni][tt] = (unsigned)__shfl_xor((int)su32[ni][tt], 32);
#pragma unroll
    for (int c = 0; c < 4; ++c) {
      int ni = c >> 1, b4 = 4 * (c & 1);
      U8 w;
      w.u[0] = hib ? X[ni][b4 + 2] : su32[ni][b4 + 0];
      w.u[1] = hib ? X[ni][b4 + 3] : su32[ni][b4 + 1];
      w.u[2] = hib ? su32[ni][b4 + 2] : X[ni][b4 + 0];
      w.u[3] = hib ? su32[ni][b4 + 3] : X[ni][b4 + 1];
      pa[c] = w.s;
    }
#endif

    if (pref) { WAITV(8); } else { WAITV(0); }  // V(t) done; K(t+1) stays in flight

    // Z^T += V^T * P
#pragma unroll
    for (int c = 0; c < 4; ++c) {
      zacc[0] = __builtin_amdgcn_mfma_f32_32x32x16_bf16(vf[0][c], pa[c], zacc[0], 0, 0, 0);
      zacc[1] = __builtin_amdgcn_mfma_f32_32x32x16_bf16(vf[1][c], pa[c], zacc[1], 0, 0, 0);
    }
  };

  int t = 0;
  while (true) {
    computeT(kfA, kfB, t);
    if (++t >= ntiles) break;
    computeT(kfB, kfA, t);
    if (++t >= ntiles) break;
  }

  // normalize + transpose Z^T -> Z via swizzled LDS, coalesced store
  const float rl = 1.0f / lrun;
  const int W8[8] = {0, 1, 4, 5, 8, 9, 12, 13};
#pragma unroll
  for (int dj = 0; dj < 2; ++dj)
#pragma unroll
    for (int tt = 0; tt < 8; ++tt) {
      unsigned v = pack2(zacc[dj][2 * tt] * rl, zacc[dj][2 * tt + 1] * rl);
      int x = 16 * dj + (hib ? 2 : 0) + W8[tt];
      Zl[qln * 32 + (((x >> 2) ^ (qln & 7)) << 2) + (x & 3)] = v;
    }
  asm volatile("s_waitcnt lgkmcnt(0)" ::: "memory");
  __builtin_amdgcn_sched_barrier(0);
  int q2 = lane >> 1, hf = lane & 1;
#pragma unroll
  for (int u = 0; u < 4; ++u) {
    int sl = (hf * 4 + u) ^ (q2 & 7);
    U8 w;
    w.u = *(const uint4v*)&Zl[q2 * 32 + sl * 4];
    *(short8*)(Zb + base + (size_t)(q0 + q2) * DM + hf * 32 + u * 8) = w.s;
  }
}

extern "C" void kernel_launch(void* const* d_in, const int* in_sizes, int n_in,
                              void* d_out, int out_size, void* d_ws, size_t ws_size,
                              hipStream_t stream) {
  (void)in_sizes; (void)n_in; (void)out_size; (void)ws_size;
  const float* x = (const float*)d_in[0];
  const float* pos = (const float*)d_in[1];
  const float* WQ = (const float*)d_in[2];
  const float* bQ = (const float*)d_in[3];
  const float* WK = (const float*)d_in[4];
  const float* bK = (const float*)d_in[5];
  const float* WV = (const float*)d_in[6];
  const float* bV = (const float*)d_in[7];
  const float* WO = (const float*)d_in[8];
  const float* bO = (const float*)d_in[9];
  float* out = (float*)d_out;

  bf16* ws = (bf16*)d_ws;
  size_t off = 0;
  bf16* aib = ws + off; off += (size_t)MROWS * DM;
  bf16* xb  = ws + off; off += (size_t)MROWS * DM;
  bf16* wqt = ws + off; off += (size_t)DM * DM;
  bf16* wkt = ws + off; off += (size_t)DM * DM;
  bf16* wvt = ws + off; off += (size_t)DM * DM;
  bf16* wot = ws + off; off += (size_t)DM * DM;
  bf16* Qb  = ws + off; off += (size_t)MROWS * DM;
  bf16* Kb  = ws + off; off += (size_t)MROWS * DM;
  bf16* Vtb = ws + off; off += (size_t)MROWS * DM;  // [bh][d][s]
  bf16* Zb  = ws + off; off += (size_t)MROWS * DM;
  // fragment-major K/V reuse dead regions (aib/xb unused after qkv_gemm)
  bf16* FK = aib;
  bf16* FV = xb;

  prep_inputs<<<(MROWS * DM / 4 + 255) / 256, 256, 0, stream>>>(x, pos, xb, aib);
  dim3 gq(1, 16, 16);
  transpose_w<<<gq, 256, 0, stream>>>(WQ, wqt, 1024, 64);
  transpose_w<<<gq, 256, 0, stream>>>(WK, wkt, 1024, 64);
  transpose_w<<<gq, 256, 0, stream>>>(WV, wvt, 1024, 64);
  dim3 go(16, 16, 1);
  transpose_w<<<go, 256, 0, stream>>>(WO, wot, 1024, 1024);
  qkv_gemm<<<768, 256, 0, stream>>>(aib, xb, wqt, wkt, wvt, bQ, bK, bV, Qb, Kb, Vtb);
  repack_k<<<dim3(32, 64), 256, 0, stream>>>(Kb, FK);
  repack_v<<<dim3(32, 2, 8), 256, 0, stream>>>(Vtb, FV);
  flash_attn<<<2048, 64, 0, stream>>>(Qb, FK, FV, Zb);
  o_gemm<<<256, 256, 0, stream>>>(Zb, wot, bO, out);
}

// Round 8
// 123.610 us; speedup vs baseline: 1.2347x; 1.1223x over previous
//
#include <hip/hip_runtime.h>
#include <hip/hip_bf16.h>
#include <stdint.h>

typedef __hip_bfloat16 bf16;
typedef __attribute__((ext_vector_type(8))) short short8;
typedef __attribute__((ext_vector_type(4))) short short4v;
typedef __attribute__((ext_vector_type(4))) float f32x4;
typedef __attribute__((ext_vector_type(16))) float f32x16;
typedef __attribute__((ext_vector_type(4))) unsigned uint4v;
typedef __attribute__((ext_vector_type(2))) unsigned uint2v;

#define AS1 __attribute__((address_space(1)))
#define AS3 __attribute__((address_space(3)))

static constexpr int SEQ = 2048, DM = 1024, DHD = 64;
static constexpr int MROWS = 2 * SEQ;  // 4096

__device__ __forceinline__ short f2b(float f) {
  __hip_bfloat16 h = __float2bfloat16(f);
  return *reinterpret_cast<short*>(&h);
}

__device__ __forceinline__ unsigned pack2(float lo, float hi) {
  float2 fv; fv.x = lo; fv.y = hi;
  union { __hip_bfloat162 h; unsigned u; } cv;
  cv.h = __float22bfloat162_rn(fv);
  return cv.u;
}

union U8 { uint4v u; short8 s; };

// volatile asm 16B global load with literal byte offset — cannot be sunk/reordered
#define GL16(dst, ptr, off) \
  asm volatile("global_load_dwordx4 %0, %1, off offset:" #off : "=v"(dst) : "v"(ptr))
// counted wait + scheduling fence (rule #18)
#define WAITV(n) do { asm volatile("s_waitcnt vmcnt(" #n ")"); __builtin_amdgcn_sched_barrier(0); } while (0)

__device__ __forceinline__ float xmax32(float v) {
#if __has_builtin(__builtin_amdgcn_permlane32_swap)
  uint2v r = __builtin_amdgcn_permlane32_swap(__float_as_uint(v), __float_as_uint(v), false, false);
  return fmaxf(__uint_as_float(r[0]), __uint_as_float(r[1]));
#else
  return fmaxf(v, __shfl_xor(v, 32));
#endif
}
__device__ __forceinline__ float xsum32(float v) {
#if __has_builtin(__builtin_amdgcn_permlane32_swap)
  uint2v r = __builtin_amdgcn_permlane32_swap(__float_as_uint(v), __float_as_uint(v), false, false);
  return __uint_as_float(r[0]) + __uint_as_float(r[1]);
#else
  return v + __shfl_xor(v, 32);
#endif
}

// ---------------- prep: x -> bf16, x+pos -> bf16 ----------------
__global__ __launch_bounds__(256) void prep_inputs(const float* __restrict__ x,
                                                   const float* __restrict__ pos,
                                                   bf16* __restrict__ xb,
                                                   bf16* __restrict__ aib) {
  int i = blockIdx.x * 256 + threadIdx.x;
  const int n4 = MROWS * DM / 4;
  if (i >= n4) return;
  f32x4 xv = ((const f32x4*)x)[i];
  f32x4 pv = ((const f32x4*)pos)[i];
  short4v xo, ao;
#pragma unroll
  for (int j = 0; j < 4; ++j) {
    xo[j] = f2b(xv[j]);
    ao[j] = f2b(xv[j] + pv[j]);
  }
  ((short4v*)xb)[i] = xo;
  ((short4v*)aib)[i] = ao;
}

// ---------------- weight transpose: [R][C] f32 -> [C][R] bf16 (per z-slice) --
__global__ __launch_bounds__(256) void transpose_w(const float* __restrict__ in,
                                                   bf16* __restrict__ out, int R, int C) {
  __shared__ float t[64][65];
  int ct = blockIdx.x, rt = blockIdx.y, z = blockIdx.z;
  in += (size_t)z * R * C;
  out += (size_t)z * R * C;
  int c = threadIdx.x & 63, g = threadIdx.x >> 6;
#pragma unroll
  for (int j = 0; j < 16; ++j) {
    int r = g * 16 + j;
    t[r][c] = in[(size_t)(rt * 64 + r) * C + (ct * 64 + c)];
  }
  __syncthreads();
#pragma unroll
  for (int j = 0; j < 16; ++j) {
    int rr = g * 16 + j;
    out[(size_t)(ct * 64 + rr) * R + (rt * 64 + c)] = __float2bfloat16(t[c][rr]);
  }
}

// ---------------- 128x128 GEMM body (A[M][1024] bf16, Bt[N][1024] bf16) -----
// MODE 1: f32 row-major out. MODE 3: bf16 fragment-major FQ/FK (flash QK
// operand layout). MODE 4: bf16 fragment-major FV (flash V^T operand layout).
template <int MODE, typename OutT>
__device__ __forceinline__ void gemm128_body(const bf16* __restrict__ A,
                                             const bf16* __restrict__ Bt,
                                             const float* __restrict__ bias,
                                             OutT* __restrict__ C, int mt, int nt,
                                             float scale) {
  __shared__ alignas(16) bf16 Al[128 * 32];
  __shared__ alignas(16) bf16 Bl[128 * 32];
  const int lane = threadIdx.x & 63, wv = threadIdx.x >> 6;
  const int wr = wv >> 1, wc = wv & 1;
  const bf16* Ab = A + (size_t)mt * 128 * DM;
  const bf16* Bb = Bt + (size_t)nt * 128 * DM;

  f32x4 acc[4][4];
#pragma unroll
  for (int i = 0; i < 4; ++i)
#pragma unroll
    for (int j = 0; j < 4; ++j) acc[i][j] = (f32x4){0.f, 0.f, 0.f, 0.f};

  for (int kt = 0; kt < DM / 32; ++kt) {
    int k0 = kt * 32;
#pragma unroll
    for (int c = 0; c < 2; ++c) {
      int li0 = wv * 64 + c * 256;
      int li = li0 + lane;
      int row = li >> 2, sl = li & 3;
      int gs = sl ^ ((row >> 1) & 3);
      __builtin_amdgcn_global_load_lds((const AS1 void*)(Ab + (size_t)row * DM + k0 + gs * 8),
                                       (AS3 void*)(&Al[li0 * 8]), 16, 0, 0);
    }
#pragma unroll
    for (int c = 0; c < 2; ++c) {
      int li0 = wv * 64 + c * 256;
      int li = li0 + lane;
      int row = li >> 2, sl = li & 3;
      int gs = sl ^ ((row >> 1) & 3);
      __builtin_amdgcn_global_load_lds((const AS1 void*)(Bb + (size_t)row * DM + k0 + gs * 8),
                                       (AS3 void*)(&Bl[li0 * 8]), 16, 0, 0);
    }
    __syncthreads();

    short8 af[4], bfr[4];
    const int kb = lane >> 4;
#pragma unroll
    for (int mi = 0; mi < 4; ++mi) {
      int r = wr * 64 + mi * 16 + (lane & 15);
      af[mi] = *(const short8*)(&Al[r * 32 + ((kb ^ ((r >> 1) & 3)) << 3)]);
    }
#pragma unroll
    for (int ni = 0; ni < 4; ++ni) {
      int r = wc * 64 + ni * 16 + (lane & 15);
      bfr[ni] = *(const short8*)(&Bl[r * 32 + ((kb ^ ((r >> 1) & 3)) << 3)]);
    }
#pragma unroll
    for (int mi = 0; mi < 4; ++mi)
#pragma unroll
      for (int ni = 0; ni < 4; ++ni)
        acc[mi][ni] = __builtin_amdgcn_mfma_f32_16x16x32_bf16(af[mi], bfr[ni], acc[mi][ni], 0, 0, 0);
    __syncthreads();
  }

#pragma unroll
  for (int mi = 0; mi < 4; ++mi) {
#pragma unroll
    for (int ni = 0; ni < 4; ++ni) {
      int row0 = mt * 128 + wr * 64 + mi * 16 + (lane >> 4) * 4;
      int col = nt * 128 + wc * 64 + ni * 16 + (lane & 15);
      float bv = bias[col];
      if constexpr (MODE == 1) {
#pragma unroll
        for (int j = 0; j < 4; ++j)
          C[(size_t)(row0 + j) * DM + col] = (acc[mi][ni][j] + bv) * scale;
      } else {
        int bb = row0 >> 11, s0 = row0 & 2047;
        int hh = col >> 6, d0 = col & 63;
        size_t bhb = (size_t)(bb * 16 + hh) * 131072;
        if constexpr (MODE == 3) {
          // FQ/FK[bh][g][kc]: slot (r32+32*hi)*8 + e, from row s, col d0
          int kc = d0 >> 4, hi = (d0 >> 3) & 1, e = d0 & 7;
          int g = s0 >> 5, r0 = s0 & 31;
          size_t bbase = bhb + g * 2048 + kc * 512 + e;
#pragma unroll
          for (int j = 0; j < 4; ++j)
            ((bf16*)C)[bbase + (size_t)(r0 + j + 32 * hi) * 8] =
                __float2bfloat16((acc[mi][ni][j] + bv) * scale);
        } else {  // MODE 4
          // FV[bh][dj][ks]: slot (d32+32*((s>>3)&1))*8 + (s&7), d on slot axis
          int dj = d0 >> 5, d32 = d0 & 31;
          int ks = s0 >> 4, hi2 = (s0 >> 3) & 1, e0 = s0 & 7;
          short4v o;
#pragma unroll
          for (int j = 0; j < 4; ++j) o[j] = f2b(acc[mi][ni][j] + bv);
          *(short4v*)((bf16*)C + bhb + dj * 65536 + ks * 512 + (size_t)(d32 + 32 * hi2) * 8 + e0) = o;
        }
      }
    }
  }
}

// Q prescale: (1/sqrt(64)) * log2(e) so attention uses exp2
static constexpr float QSCALE = 0.125f * 1.4426950408889634f;

__global__ __launch_bounds__(256) void qkv_gemm(const bf16* __restrict__ aib,
                                                const bf16* __restrict__ xb,
                                                const bf16* __restrict__ wqt,
                                                const bf16* __restrict__ wkt,
                                                const bf16* __restrict__ wvt,
                                                const float* __restrict__ bq,
                                                const float* __restrict__ bk,
                                                const float* __restrict__ bv,
                                                bf16* __restrict__ FQ, bf16* __restrict__ FK,
                                                bf16* __restrict__ FV) {
  int mt = blockIdx.x & 31;
  int nt = (blockIdx.x >> 5) & 7;
  int mat = blockIdx.x >> 8;
  if (mat == 0) {
    gemm128_body<3>(aib, wqt, bq, FQ, mt, nt, QSCALE);
  } else if (mat == 1) {
    gemm128_body<3>(aib, wkt, bk, FK, mt, nt, 1.0f);
  } else {
    gemm128_body<4>(xb, wvt, bv, FV, mt, nt, 1.0f);
  }
}

__global__ __launch_bounds__(256) void o_gemm(const bf16* __restrict__ Z,
                                              const bf16* __restrict__ wot,
                                              const float* __restrict__ bo,
                                              float* __restrict__ out) {
  int mt = blockIdx.x & 31;
  int nt = blockIdx.x >> 5;
  gemm128_body<1>(Z, wot, bo, out, mt, nt, 1.0f);
}

// ---------------- flash attention: split-KV x2, swapped-QK^T ----------------
// 128-thread block = 2 waves on one (bh, q-tile). Wave0 computes KV tiles
// [0,hsp), wave1 [hsp,nt), each with private online softmax; exact merge via
// LDS. All operands fragment-major (FQ/FK/FV) -> every load is a coalesced
// 1KB global_load_dwordx4 with counted-vmcnt pipelining.
// launch_bounds (128,2): 256-VGPR cap. (128,4) capped at 128 and spilled
// in-flight asm-load destinations -> NaN (compiler can't see vmcnt deps).
__global__ __launch_bounds__(128, 2) void flash_attn(const bf16* __restrict__ FQ,
                                                     const bf16* __restrict__ FK,
                                                     const bf16* __restrict__ FV,
                                                     bf16* __restrict__ Zb) {
  __shared__ float Zm[64][33];   // wave1 partial Z^T (padded)
  __shared__ float Ml[64], Ll[64];
  __shared__ unsigned Zl[32 * 32];  // wave0 final ZT->Z transpose

  const int lane = threadIdx.x & 63;
  const int wvi = threadIdx.x >> 6;
  const int qln = lane & 31;
  const bool hib = lane >= 32;
  const int bh = blockIdx.x & 31;           // bh%8 -> XCD affinity
  const int wq = 63 - (blockIdx.x >> 5);    // heavy blocks dispatch first
  const int bb = bh >> 4, h = bh & 15;
  const int q0 = wq * 32;
  const int nt = wq / 2 + 1;
  const int hsp = (nt + 1) >> 1;
  const int t0 = wvi ? hsp : 0;
  const int t1 = wvi ? nt : hsp;

  const size_t fb = (size_t)bh * 131072;
  const bf16* qp = FQ + fb + wq * 2048 + lane * 8;
  const bf16* kpt = FK + fb + (size_t)t0 * 4096 + lane * 8;
  const bf16* vp0 = FV + fb + (size_t)t0 * 2048 + lane * 8;
  const bf16* vp1 = vp0 + 65536;

  f32x16 zacc[2];
#pragma unroll
  for (int i = 0; i < 16; ++i) { zacc[0][i] = 0.f; zacc[1][i] = 0.f; }
  float mrun = -1e30f, lrun = 0.f;

  short8 qf[4];
  short8 kfA[2][4], kfB[2][4];

  if (t0 < t1) {
    // prologue: Q (4 loads) then K(t0) (8 coalesced loads)
    GL16(qf[0], qp, 0); GL16(qf[1], qp, 1024); GL16(qf[2], qp, 2048); GL16(qf[3], qp, 3072);
    {
      const bf16* k1 = kpt + 2048;
      GL16(kfA[0][0], kpt, 0); GL16(kfA[0][1], kpt, 1024); GL16(kfA[0][2], kpt, 2048); GL16(kfA[0][3], kpt, 3072);
      GL16(kfA[1][0], k1, 0);  GL16(kfA[1][1], k1, 1024);  GL16(kfA[1][2], k1, 2048);  GL16(kfA[1][3], k1, 3072);
      kpt += 4096;
    }

    auto computeT = [&](short8(&kf)[2][4], short8(&kfn)[2][4], int t) {
      const int kv0 = t * 64;
      const bool pref = (t + 1 < t1);

      // issue V(t) — consumed at PV below
      short8 vf[2][4];
      GL16(vf[0][0], vp0, 0); GL16(vf[0][1], vp0, 1024); GL16(vf[0][2], vp0, 2048); GL16(vf[0][3], vp0, 3072);
      GL16(vf[1][0], vp1, 0); GL16(vf[1][1], vp1, 1024); GL16(vf[1][2], vp1, 2048); GL16(vf[1][3], vp1, 3072);
      vp0 += 2048; vp1 += 2048;

      WAITV(8);  // K(t) (and Q on first tile) complete; V(t) stays in flight

      f32x16 s[2];
#pragma unroll
      for (int i = 0; i < 16; ++i) { s[0][i] = 0.f; s[1][i] = 0.f; }
#pragma unroll
      for (int kc = 0; kc < 4; ++kc) {
        s[0] = __builtin_amdgcn_mfma_f32_32x32x16_bf16(kf[0][kc], qf[kc], s[0], 0, 0, 0);
        s[1] = __builtin_amdgcn_mfma_f32_32x32x16_bf16(kf[1][kc], qf[kc], s[1], 0, 0, 0);
      }

      if (pref) {  // issue K(t+1)
        const bf16* k1 = kpt + 2048;
        GL16(kfn[0][0], kpt, 0); GL16(kfn[0][1], kpt, 1024); GL16(kfn[0][2], kpt, 2048); GL16(kfn[0][3], kpt, 3072);
        GL16(kfn[1][0], k1, 0);  GL16(kfn[1][1], k1, 1024);  GL16(kfn[1][2], k1, 2048);  GL16(kfn[1][3], k1, 3072);
        kpt += 4096;
      }

      if (t == nt - 1) {  // causal mask, diagonal tile only
        const int qg = q0 + qln;
#pragma unroll
        for (int ni = 0; ni < 2; ++ni)
#pragma unroll
          for (int rr = 0; rr < 16; ++rr) {
            int kv = kv0 + 32 * ni + (rr & 3) + 8 * (rr >> 2) + (hib ? 4 : 0);
            if (kv > qg) s[ni][rr] = -1e30f;
          }
      }

      // row max: in-register tree + cross-half swap
      float t8[8];
#pragma unroll
      for (int i = 0; i < 8; ++i)
        t8[i] = fmaxf(fmaxf(s[0][i], s[0][i + 8]), fmaxf(s[1][i], s[1][i + 8]));
      float tm = fmaxf(fmaxf(fmaxf(t8[0], t8[1]), fmaxf(t8[2], t8[3])),
                       fmaxf(fmaxf(t8[4], t8[5]), fmaxf(t8[6], t8[7])));
      tm = xmax32(tm);

      // defer-max: rescale only if the running max grew (exact)
      if (__ballot(tm > mrun)) {
        float mn = fmaxf(mrun, tm);
        float al = exp2f(mrun - mn);
        mrun = mn;
        lrun *= al;
#pragma unroll
        for (int i = 0; i < 16; ++i) { zacc[0][i] *= al; zacc[1][i] *= al; }
      }

      float pacc[4] = {0.f, 0.f, 0.f, 0.f};
#pragma unroll
      for (int ni = 0; ni < 2; ++ni)
#pragma unroll
        for (int rr = 0; rr < 16; ++rr) {
          float p = exp2f(s[ni][rr] - mrun);
          s[ni][rr] = p;
          pacc[rr & 3] += p;
        }
      lrun += xsum32((pacc[0] + pacc[1]) + (pacc[2] + pacc[3]));

      // P -> bf16 B-fragments: pack pairs, permlane32_swap fills both halves
      unsigned su32[2][8];
#pragma unroll
      for (int ni = 0; ni < 2; ++ni)
#pragma unroll
        for (int tt = 0; tt < 8; ++tt)
          su32[ni][tt] = pack2(s[ni][2 * tt], s[ni][2 * tt + 1]);

      short8 pa[4];
#if __has_builtin(__builtin_amdgcn_permlane32_swap)
#pragma unroll
      for (int c = 0; c < 4; ++c) {
        int ni = c >> 1, b4 = 4 * (c & 1);
        uint2v r0 = __builtin_amdgcn_permlane32_swap(su32[ni][b4 + 0], su32[ni][b4 + 2], false, false);
        uint2v r1 = __builtin_amdgcn_permlane32_swap(su32[ni][b4 + 1], su32[ni][b4 + 3], false, false);
        U8 w;
        w.u[0] = r0[0]; w.u[1] = r1[0]; w.u[2] = r0[1]; w.u[3] = r1[1];
        pa[c] = w.s;
      }
#else
      unsigned X[2][8];
#pragma unroll
      for (int ni = 0; ni < 2; ++ni)
#pragma unroll
        for (int tt = 0; tt < 8; ++tt)
          X[ni][tt] = (unsigned)__shfl_xor((int)su32[ni][tt], 32);
#pragma unroll
      for (int c = 0; c < 4; ++c) {
        int ni = c >> 1, b4 = 4 * (c & 1);
        U8 w;
        w.u[0] = hib ? X[ni][b4 + 2] : su32[ni][b4 + 0];
        w.u[1] = hib ? X[ni][b4 + 3] : su32[ni][b4 + 1];
        w.u[2] = hib ? su32[ni][b4 + 2] : X[ni][b4 + 0];
        w.u[3] = hib ? su32[ni][b4 + 3] : X[ni][b4 + 1];
        pa[c] = w.s;
      }
#endif

      if (pref) { WAITV(8); } else { WAITV(0); }  // V(t) done; K(t+1) in flight

#pragma unroll
      for (int c = 0; c < 4; ++c) {
        zacc[0] = __builtin_amdgcn_mfma_f32_32x32x16_bf16(vf[0][c], pa[c], zacc[0], 0, 0, 0);
        zacc[1] = __builtin_amdgcn_mfma_f32_32x32x16_bf16(vf[1][c], pa[c], zacc[1], 0, 0, 0);
      }
    };

    int t = t0;
    while (true) {
      computeT(kfA, kfB, t);
      if (++t >= t1) break;
      computeT(kfB, kfA, t);
      if (++t >= t1) break;
    }
  }

  // ---- merge wave1 into wave0 (exact online-softmax combine) ----
  if (wvi == 1) {
#pragma unroll
    for (int i = 0; i < 16; ++i) {
      Zm[lane][i] = zacc[0][i];
      Zm[lane][16 + i] = zacc[1][i];
    }
    Ml[lane] = mrun;
    Ll[lane] = lrun;
  }
  __syncthreads();
  if (wvi == 0) {
    float m1 = Ml[lane], l1 = Ll[lane];
    float mn = fmaxf(mrun, m1);
    float a0 = exp2f(mrun - mn);
    float a1 = exp2f(m1 - mn);
    float lm = lrun * a0 + l1 * a1;
#pragma unroll
    for (int i = 0; i < 16; ++i) {
      zacc[0][i] = zacc[0][i] * a0 + Zm[lane][i] * a1;
      zacc[1][i] = zacc[1][i] * a0 + Zm[lane][16 + i] * a1;
    }

    // normalize + transpose Z^T -> Z via swizzled LDS, coalesced store
    const float rl = 1.0f / lm;
    const int W8[8] = {0, 1, 4, 5, 8, 9, 12, 13};
#pragma unroll
    for (int dj = 0; dj < 2; ++dj)
#pragma unroll
      for (int tt = 0; tt < 8; ++tt) {
        unsigned v = pack2(zacc[dj][2 * tt] * rl, zacc[dj][2 * tt + 1] * rl);
        int x = 16 * dj + (hib ? 2 : 0) + W8[tt];
        Zl[qln * 32 + (((x >> 2) ^ (qln & 7)) << 2) + (x & 3)] = v;
      }
    asm volatile("s_waitcnt lgkmcnt(0)" ::: "memory");
    __builtin_amdgcn_sched_barrier(0);
    const size_t base = ((size_t)bb * SEQ) * DM + h * DHD;
    int q2 = lane >> 1, hf = lane & 1;
#pragma unroll
    for (int u = 0; u < 4; ++u) {
      int sl = (hf * 4 + u) ^ (q2 & 7);
      U8 w;
      w.u = *(const uint4v*)&Zl[q2 * 32 + sl * 4];
      *(short8*)(Zb + base + (size_t)(q0 + q2) * DM + hf * 32 + u * 8) = w.s;
    }
  }
}

extern "C" void kernel_launch(void* const* d_in, const int* in_sizes, int n_in,
                              void* d_out, int out_size, void* d_ws, size_t ws_size,
                              hipStream_t stream) {
  (void)in_sizes; (void)n_in; (void)out_size; (void)ws_size;
  const float* x = (const float*)d_in[0];
  const float* pos = (const float*)d_in[1];
  const float* WQ = (const float*)d_in[2];
  const float* bQ = (const float*)d_in[3];
  const float* WK = (const float*)d_in[4];
  const float* bK = (const float*)d_in[5];
  const float* WV = (const float*)d_in[6];
  const float* bV = (const float*)d_in[7];
  const float* WO = (const float*)d_in[8];
  const float* bO = (const float*)d_in[9];
  float* out = (float*)d_out;

  bf16* ws = (bf16*)d_ws;
  size_t off = 0;
  bf16* aib = ws + off; off += (size_t)MROWS * DM;
  bf16* xb  = ws + off; off += (size_t)MROWS * DM;
  bf16* wqt = ws + off; off += (size_t)DM * DM;
  bf16* wkt = ws + off; off += (size_t)DM * DM;
  bf16* wvt = ws + off; off += (size_t)DM * DM;
  bf16* wot = ws + off; off += (size_t)DM * DM;
  bf16* FQ  = ws + off; off += (size_t)MROWS * DM;  // fragment-major [bh][g][kc]
  bf16* FK  = ws + off; off += (size_t)MROWS * DM;
  bf16* FV  = ws + off; off += (size_t)MROWS * DM;  // fragment-major [bh][dj][ks]
  bf16* Zb  = ws + off; off += (size_t)MROWS * DM;

  prep_inputs<<<(MROWS * DM / 4 + 255) / 256, 256, 0, stream>>>(x, pos, xb, aib);
  dim3 gq(1, 16, 16);
  transpose_w<<<gq, 256, 0, stream>>>(WQ, wqt, 1024, 64);
  transpose_w<<<gq, 256, 0, stream>>>(WK, wkt, 1024, 64);
  transpose_w<<<gq, 256, 0, stream>>>(WV, wvt, 1024, 64);
  dim3 go(16, 16, 1);
  transpose_w<<<go, 256, 0, stream>>>(WO, wot, 1024, 1024);
  qkv_gemm<<<768, 256, 0, stream>>>(aib, xb, wqt, wkt, wvt, bQ, bK, bV, FQ, FK, FV);
  flash_attn<<<2048, 128, 0, stream>>>(FQ, FK, FV, Zb);
  o_gemm<<<256, 256, 0, stream>>>(Zb, wot, bO, out);
}

// Round 9
// 113.361 us; speedup vs baseline: 1.3464x; 1.0904x over previous
//
#include <hip/hip_runtime.h>
#include <hip/hip_bf16.h>
#include <stdint.h>

typedef __hip_bfloat16 bf16;
typedef __attribute__((ext_vector_type(8))) short short8;
typedef __attribute__((ext_vector_type(4))) short short4v;
typedef __attribute__((ext_vector_type(4))) float f32x4;
typedef __attribute__((ext_vector_type(16))) float f32x16;
typedef __attribute__((ext_vector_type(4))) unsigned uint4v;
typedef __attribute__((ext_vector_type(2))) unsigned uint2v;

#define AS1 __attribute__((address_space(1)))
#define AS3 __attribute__((address_space(3)))

static constexpr int SEQ = 2048, DM = 1024, DHD = 64;
static constexpr int MROWS = 2 * SEQ;  // 4096

__device__ __forceinline__ short f2b(float f) {
  __hip_bfloat16 h = __float2bfloat16(f);
  return *reinterpret_cast<short*>(&h);
}

__device__ __forceinline__ unsigned pack2(float lo, float hi) {
  float2 fv; fv.x = lo; fv.y = hi;
  union { __hip_bfloat162 h; unsigned u; } cv;
  cv.h = __float22bfloat162_rn(fv);
  return cv.u;
}

// raw v_exp_f32 (1-inst exp2) — libm exp2f carries range-check bloat
__device__ __forceinline__ float fexp2(float x) {
#if __has_builtin(__builtin_amdgcn_exp2f)
  return __builtin_amdgcn_exp2f(x);
#else
  return exp2f(x);
#endif
}

union U8 { uint4v u; short8 s; };

// volatile asm 16B global load with literal byte offset — cannot be sunk/reordered
#define GL16(dst, ptr, off) \
  asm volatile("global_load_dwordx4 %0, %1, off offset:" #off : "=v"(dst) : "v"(ptr))
// counted wait + scheduling fence (rule #18)
#define WAITV(n) do { asm volatile("s_waitcnt vmcnt(" #n ")"); __builtin_amdgcn_sched_barrier(0); } while (0)

__device__ __forceinline__ float xmax32(float v) {
#if __has_builtin(__builtin_amdgcn_permlane32_swap)
  uint2v r = __builtin_amdgcn_permlane32_swap(__float_as_uint(v), __float_as_uint(v), false, false);
  return fmaxf(__uint_as_float(r[0]), __uint_as_float(r[1]));
#else
  return fmaxf(v, __shfl_xor(v, 32));
#endif
}
__device__ __forceinline__ float xsum32(float v) {
#if __has_builtin(__builtin_amdgcn_permlane32_swap)
  uint2v r = __builtin_amdgcn_permlane32_swap(__float_as_uint(v), __float_as_uint(v), false, false);
  return __uint_as_float(r[0]) + __uint_as_float(r[1]);
#else
  return v + __shfl_xor(v, 32);
#endif
}

// ---------------- prep: x -> bf16, x+pos -> bf16 ----------------
__global__ __launch_bounds__(256) void prep_inputs(const float* __restrict__ x,
                                                   const float* __restrict__ pos,
                                                   bf16* __restrict__ xb,
                                                   bf16* __restrict__ aib) {
  int i = blockIdx.x * 256 + threadIdx.x;
  const int n4 = MROWS * DM / 4;
  if (i >= n4) return;
  f32x4 xv = ((const f32x4*)x)[i];
  f32x4 pv = ((const f32x4*)pos)[i];
  short4v xo, ao;
#pragma unroll
  for (int j = 0; j < 4; ++j) {
    xo[j] = f2b(xv[j]);
    ao[j] = f2b(xv[j] + pv[j]);
  }
  ((short4v*)xb)[i] = xo;
  ((short4v*)aib)[i] = ao;
}

// ---------------- weight transpose: [R][C] f32 -> [C][R] bf16 (per z-slice) --
__global__ __launch_bounds__(256) void transpose_w(const float* __restrict__ in,
                                                   bf16* __restrict__ out, int R, int C) {
  __shared__ float t[64][65];
  int ct = blockIdx.x, rt = blockIdx.y, z = blockIdx.z;
  in += (size_t)z * R * C;
  out += (size_t)z * R * C;
  int c = threadIdx.x & 63, g = threadIdx.x >> 6;
#pragma unroll
  for (int j = 0; j < 16; ++j) {
    int r = g * 16 + j;
    t[r][c] = in[(size_t)(rt * 64 + r) * C + (ct * 64 + c)];
  }
  __syncthreads();
#pragma unroll
  for (int j = 0; j < 16; ++j) {
    int rr = g * 16 + j;
    out[(size_t)(ct * 64 + rr) * R + (rt * 64 + c)] = __float2bfloat16(t[c][rr]);
  }
}

// ---------------- 128x128 GEMM body (A[M][1024] bf16, Bt[N][1024] bf16) -----
// MODE 1: f32 row-major out. MODE 3: bf16 fragment-major FQ/FK (flash QK
// operand layout). MODE 4: bf16 fragment-major FV (flash V^T operand layout).
template <int MODE, typename OutT>
__device__ __forceinline__ void gemm128_body(const bf16* __restrict__ A,
                                             const bf16* __restrict__ Bt,
                                             const float* __restrict__ bias,
                                             OutT* __restrict__ C, int mt, int nt,
                                             float scale) {
  __shared__ alignas(16) bf16 Al[128 * 32];
  __shared__ alignas(16) bf16 Bl[128 * 32];
  const int lane = threadIdx.x & 63, wv = threadIdx.x >> 6;
  const int wr = wv >> 1, wc = wv & 1;
  const bf16* Ab = A + (size_t)mt * 128 * DM;
  const bf16* Bb = Bt + (size_t)nt * 128 * DM;

  f32x4 acc[4][4];
#pragma unroll
  for (int i = 0; i < 4; ++i)
#pragma unroll
    for (int j = 0; j < 4; ++j) acc[i][j] = (f32x4){0.f, 0.f, 0.f, 0.f};

  for (int kt = 0; kt < DM / 32; ++kt) {
    int k0 = kt * 32;
#pragma unroll
    for (int c = 0; c < 2; ++c) {
      int li0 = wv * 64 + c * 256;
      int li = li0 + lane;
      int row = li >> 2, sl = li & 3;
      int gs = sl ^ ((row >> 1) & 3);
      __builtin_amdgcn_global_load_lds((const AS1 void*)(Ab + (size_t)row * DM + k0 + gs * 8),
                                       (AS3 void*)(&Al[li0 * 8]), 16, 0, 0);
    }
#pragma unroll
    for (int c = 0; c < 2; ++c) {
      int li0 = wv * 64 + c * 256;
      int li = li0 + lane;
      int row = li >> 2, sl = li & 3;
      int gs = sl ^ ((row >> 1) & 3);
      __builtin_amdgcn_global_load_lds((const AS1 void*)(Bb + (size_t)row * DM + k0 + gs * 8),
                                       (AS3 void*)(&Bl[li0 * 8]), 16, 0, 0);
    }
    __syncthreads();

    short8 af[4], bfr[4];
    const int kb = lane >> 4;
#pragma unroll
    for (int mi = 0; mi < 4; ++mi) {
      int r = wr * 64 + mi * 16 + (lane & 15);
      af[mi] = *(const short8*)(&Al[r * 32 + ((kb ^ ((r >> 1) & 3)) << 3)]);
    }
#pragma unroll
    for (int ni = 0; ni < 4; ++ni) {
      int r = wc * 64 + ni * 16 + (lane & 15);
      bfr[ni] = *(const short8*)(&Bl[r * 32 + ((kb ^ ((r >> 1) & 3)) << 3)]);
    }
#pragma unroll
    for (int mi = 0; mi < 4; ++mi)
#pragma unroll
      for (int ni = 0; ni < 4; ++ni)
        acc[mi][ni] = __builtin_amdgcn_mfma_f32_16x16x32_bf16(af[mi], bfr[ni], acc[mi][ni], 0, 0, 0);
    __syncthreads();
  }

#pragma unroll
  for (int mi = 0; mi < 4; ++mi) {
#pragma unroll
    for (int ni = 0; ni < 4; ++ni) {
      int row0 = mt * 128 + wr * 64 + mi * 16 + (lane >> 4) * 4;
      int col = nt * 128 + wc * 64 + ni * 16 + (lane & 15);
      float bv = bias[col];
      if constexpr (MODE == 1) {
#pragma unroll
        for (int j = 0; j < 4; ++j)
          C[(size_t)(row0 + j) * DM + col] = (acc[mi][ni][j] + bv) * scale;
      } else {
        int bb = row0 >> 11, s0 = row0 & 2047;
        int hh = col >> 6, d0 = col & 63;
        size_t bhb = (size_t)(bb * 16 + hh) * 131072;
        if constexpr (MODE == 3) {
          // FQ/FK[bh][g][kc]: slot (r32+32*hi)*8 + e, from row s, col d0
          int kc = d0 >> 4, hi = (d0 >> 3) & 1, e = d0 & 7;
          int g = s0 >> 5, r0 = s0 & 31;
          size_t bbase = bhb + g * 2048 + kc * 512 + e;
#pragma unroll
          for (int j = 0; j < 4; ++j)
            ((bf16*)C)[bbase + (size_t)(r0 + j + 32 * hi) * 8] =
                __float2bfloat16((acc[mi][ni][j] + bv) * scale);
        } else {  // MODE 4
          // FV[bh][dj][ks]: slot (d32+32*((s>>3)&1))*8 + (s&7), d on slot axis
          int dj = d0 >> 5, d32 = d0 & 31;
          int ks = s0 >> 4, hi2 = (s0 >> 3) & 1, e0 = s0 & 7;
          short4v o;
#pragma unroll
          for (int j = 0; j < 4; ++j) o[j] = f2b(acc[mi][ni][j] + bv);
          *(short4v*)((bf16*)C + bhb + dj * 65536 + ks * 512 + (size_t)(d32 + 32 * hi2) * 8 + e0) = o;
        }
      }
    }
  }
}

// Q prescale: (1/sqrt(64)) * log2(e) so attention uses exp2
static constexpr float QSCALE = 0.125f * 1.4426950408889634f;

__global__ __launch_bounds__(256) void qkv_gemm(const bf16* __restrict__ aib,
                                                const bf16* __restrict__ xb,
                                                const bf16* __restrict__ wqt,
                                                const bf16* __restrict__ wkt,
                                                const bf16* __restrict__ wvt,
                                                const float* __restrict__ bq,
                                                const float* __restrict__ bk,
                                                const float* __restrict__ bv,
                                                bf16* __restrict__ FQ, bf16* __restrict__ FK,
                                                bf16* __restrict__ FV) {
  int mt = blockIdx.x & 31;
  int nt = (blockIdx.x >> 5) & 7;
  int mat = blockIdx.x >> 8;
  if (mat == 0) {
    gemm128_body<3>(aib, wqt, bq, FQ, mt, nt, QSCALE);
  } else if (mat == 1) {
    gemm128_body<3>(aib, wkt, bk, FK, mt, nt, 1.0f);
  } else {
    gemm128_body<4>(xb, wvt, bv, FV, mt, nt, 1.0f);
  }
}

// ---------------- o_gemm: 64x128 tiles -> 512 blocks (2 blocks/CU) ----------
__global__ __launch_bounds__(256) void o_gemm64(const bf16* __restrict__ A,
                                                const bf16* __restrict__ Bt,
                                                const float* __restrict__ bias,
                                                float* __restrict__ out) {
  __shared__ alignas(16) bf16 Al[64 * 32];
  __shared__ alignas(16) bf16 Bl[128 * 32];
  const int mt = blockIdx.x & 63, nt = blockIdx.x >> 6;
  const int lane = threadIdx.x & 63, wv = threadIdx.x >> 6;
  const int wr = wv >> 1, wc = wv & 1;  // wave: 32 rows x 64 cols quadrant
  const bf16* Ab = A + (size_t)mt * 64 * DM;
  const bf16* Bb = Bt + (size_t)nt * 128 * DM;

  f32x4 acc[2][4];
#pragma unroll
  for (int i = 0; i < 2; ++i)
#pragma unroll
    for (int j = 0; j < 4; ++j) acc[i][j] = (f32x4){0.f, 0.f, 0.f, 0.f};

  for (int kt = 0; kt < DM / 32; ++kt) {
    int k0 = kt * 32;
    {  // A: 64x32 = 4KB, one chunk
      int li0 = wv * 64;
      int li = li0 + lane;
      int row = li >> 2, sl = li & 3;
      int gs = sl ^ ((row >> 1) & 3);
      __builtin_amdgcn_global_load_lds((const AS1 void*)(Ab + (size_t)row * DM + k0 + gs * 8),
                                       (AS3 void*)(&Al[li0 * 8]), 16, 0, 0);
    }
#pragma unroll
    for (int c = 0; c < 2; ++c) {  // B: 128x32 = 8KB, two chunks
      int li0 = wv * 64 + c * 256;
      int li = li0 + lane;
      int row = li >> 2, sl = li & 3;
      int gs = sl ^ ((row >> 1) & 3);
      __builtin_amdgcn_global_load_lds((const AS1 void*)(Bb + (size_t)row * DM + k0 + gs * 8),
                                       (AS3 void*)(&Bl[li0 * 8]), 16, 0, 0);
    }
    __syncthreads();

    short8 af[2], bfr[4];
    const int kb = lane >> 4;
#pragma unroll
    for (int mi = 0; mi < 2; ++mi) {
      int r = wr * 32 + mi * 16 + (lane & 15);
      af[mi] = *(const short8*)(&Al[r * 32 + ((kb ^ ((r >> 1) & 3)) << 3)]);
    }
#pragma unroll
    for (int ni = 0; ni < 4; ++ni) {
      int r = wc * 64 + ni * 16 + (lane & 15);
      bfr[ni] = *(const short8*)(&Bl[r * 32 + ((kb ^ ((r >> 1) & 3)) << 3)]);
    }
#pragma unroll
    for (int mi = 0; mi < 2; ++mi)
#pragma unroll
      for (int ni = 0; ni < 4; ++ni)
        acc[mi][ni] = __builtin_amdgcn_mfma_f32_16x16x32_bf16(af[mi], bfr[ni], acc[mi][ni], 0, 0, 0);
    __syncthreads();
  }

#pragma unroll
  for (int mi = 0; mi < 2; ++mi) {
#pragma unroll
    for (int ni = 0; ni < 4; ++ni) {
      int row0 = mt * 64 + wr * 32 + mi * 16 + (lane >> 4) * 4;
      int col = nt * 128 + wc * 64 + ni * 16 + (lane & 15);
      float bv = bias[col];
#pragma unroll
      for (int j = 0; j < 4; ++j)
        out[(size_t)(row0 + j) * DM + col] = acc[mi][ni][j] + bv;
    }
  }
}

// ---------------- flash attention: split-KV x2, swapped-QK^T ----------------
// 128-thread block = 2 waves on one (bh, q-tile); wave0 tiles [0,hsp), wave1
// [hsp,nt); exact merge via LDS. Fragment-major operands -> coalesced 1KB
// loads with counted-vmcnt pipelining. THR=8 defer-max (T13, exact math).
__global__ __launch_bounds__(128, 2) void flash_attn(const bf16* __restrict__ FQ,
                                                     const bf16* __restrict__ FK,
                                                     const bf16* __restrict__ FV,
                                                     bf16* __restrict__ Zb) {
  __shared__ float Zm[64][33];   // wave1 partial Z^T (padded)
  __shared__ float Ml[64], Ll[64];
  __shared__ unsigned Zl[32 * 32];  // wave0 final ZT->Z transpose

  const int lane = threadIdx.x & 63;
  const int wvi = threadIdx.x >> 6;
  const int qln = lane & 31;
  const bool hib = lane >= 32;
  const int bh = blockIdx.x & 31;           // bh%8 -> XCD affinity
  const int wq = 63 - (blockIdx.x >> 5);    // heavy blocks dispatch first
  const int bb = bh >> 4, h = bh & 15;
  const int q0 = wq * 32;
  const int nt = wq / 2 + 1;
  const int hsp = (nt + 1) >> 1;
  const int t0 = wvi ? hsp : 0;
  const int t1 = wvi ? nt : hsp;

  const size_t fb = (size_t)bh * 131072;
  const bf16* qp = FQ + fb + wq * 2048 + lane * 8;
  const bf16* kpt = FK + fb + (size_t)t0 * 4096 + lane * 8;
  const bf16* vp0 = FV + fb + (size_t)t0 * 2048 + lane * 8;
  const bf16* vp1 = vp0 + 65536;

  f32x16 zacc[2];
#pragma unroll
  for (int i = 0; i < 16; ++i) { zacc[0][i] = 0.f; zacc[1][i] = 0.f; }
  float mrun = -1e30f, lrun = 0.f;

  short8 qf[4];
  short8 kfA[2][4], kfB[2][4];

  if (t0 < t1) {
    // prologue: Q (4 loads) then K(t0) (8 coalesced loads)
    GL16(qf[0], qp, 0); GL16(qf[1], qp, 1024); GL16(qf[2], qp, 2048); GL16(qf[3], qp, 3072);
    {
      const bf16* k1 = kpt + 2048;
      GL16(kfA[0][0], kpt, 0); GL16(kfA[0][1], kpt, 1024); GL16(kfA[0][2], kpt, 2048); GL16(kfA[0][3], kpt, 3072);
      GL16(kfA[1][0], k1, 0);  GL16(kfA[1][1], k1, 1024);  GL16(kfA[1][2], k1, 2048);  GL16(kfA[1][3], k1, 3072);
      kpt += 4096;
    }

    auto computeT = [&](short8(&kf)[2][4], short8(&kfn)[2][4], int t) {
      const int kv0 = t * 64;
      const bool pref = (t + 1 < t1);

      // issue V(t) — consumed at PV below
      short8 vf[2][4];
      GL16(vf[0][0], vp0, 0); GL16(vf[0][1], vp0, 1024); GL16(vf[0][2], vp0, 2048); GL16(vf[0][3], vp0, 3072);
      GL16(vf[1][0], vp1, 0); GL16(vf[1][1], vp1, 1024); GL16(vf[1][2], vp1, 2048); GL16(vf[1][3], vp1, 3072);
      vp0 += 2048; vp1 += 2048;

      WAITV(8);  // K(t) (and Q on first tile) complete; V(t) stays in flight

      f32x16 s[2];
#pragma unroll
      for (int i = 0; i < 16; ++i) { s[0][i] = 0.f; s[1][i] = 0.f; }
#pragma unroll
      for (int kc = 0; kc < 4; ++kc) {
        s[0] = __builtin_amdgcn_mfma_f32_32x32x16_bf16(kf[0][kc], qf[kc], s[0], 0, 0, 0);
        s[1] = __builtin_amdgcn_mfma_f32_32x32x16_bf16(kf[1][kc], qf[kc], s[1], 0, 0, 0);
      }

      if (pref) {  // issue K(t+1)
        const bf16* k1 = kpt + 2048;
        GL16(kfn[0][0], kpt, 0); GL16(kfn[0][1], kpt, 1024); GL16(kfn[0][2], kpt, 2048); GL16(kfn[0][3], kpt, 3072);
        GL16(kfn[1][0], k1, 0);  GL16(kfn[1][1], k1, 1024);  GL16(kfn[1][2], k1, 2048);  GL16(kfn[1][3], k1, 3072);
        kpt += 4096;
      }

      if (t == nt - 1) {  // causal mask, diagonal tile only
        const int qg = q0 + qln;
#pragma unroll
        for (int ni = 0; ni < 2; ++ni)
#pragma unroll
          for (int rr = 0; rr < 16; ++rr) {
            int kv = kv0 + 32 * ni + (rr & 3) + 8 * (rr >> 2) + (hib ? 4 : 0);
            if (kv > qg) s[ni][rr] = -1e30f;
          }
      }

      // row max: in-register tree + cross-half swap
      float t8[8];
#pragma unroll
      for (int i = 0; i < 8; ++i)
        t8[i] = fmaxf(fmaxf(s[0][i], s[0][i + 8]), fmaxf(s[1][i], s[1][i + 8]));
      float tm = fmaxf(fmaxf(fmaxf(t8[0], t8[1]), fmaxf(t8[2], t8[3])),
                       fmaxf(fmaxf(t8[4], t8[5]), fmaxf(t8[6], t8[7])));
      tm = xmax32(tm);

      // defer-max (T13): rescale only when max grew by >8; P bounded by 2^8,
      // math stays exact (mrun is just the reference point).
      if (__ballot(tm > mrun + 8.0f)) {
        float mn = fmaxf(mrun, tm);
        float al = fexp2(mrun - mn);
        mrun = mn;
        lrun *= al;
#pragma unroll
        for (int i = 0; i < 16; ++i) { zacc[0][i] *= al; zacc[1][i] *= al; }
      }

      float pacc[4] = {0.f, 0.f, 0.f, 0.f};
#pragma unroll
      for (int ni = 0; ni < 2; ++ni)
#pragma unroll
        for (int rr = 0; rr < 16; ++rr) {
          float p = fexp2(s[ni][rr] - mrun);
          s[ni][rr] = p;
          pacc[rr & 3] += p;
        }
      lrun += xsum32((pacc[0] + pacc[1]) + (pacc[2] + pacc[3]));

      // P -> bf16 B-fragments: pack pairs, permlane32_swap fills both halves
      unsigned su32[2][8];
#pragma unroll
      for (int ni = 0; ni < 2; ++ni)
#pragma unroll
        for (int tt = 0; tt < 8; ++tt)
          su32[ni][tt] = pack2(s[ni][2 * tt], s[ni][2 * tt + 1]);

      short8 pa[4];
#if __has_builtin(__builtin_amdgcn_permlane32_swap)
#pragma unroll
      for (int c = 0; c < 4; ++c) {
        int ni = c >> 1, b4 = 4 * (c & 1);
        uint2v r0 = __builtin_amdgcn_permlane32_swap(su32[ni][b4 + 0], su32[ni][b4 + 2], false, false);
        uint2v r1 = __builtin_amdgcn_permlane32_swap(su32[ni][b4 + 1], su32[ni][b4 + 3], false, false);
        U8 w;
        w.u[0] = r0[0]; w.u[1] = r1[0]; w.u[2] = r0[1]; w.u[3] = r1[1];
        pa[c] = w.s;
      }
#else
      unsigned X[2][8];
#pragma unroll
      for (int ni = 0; ni < 2; ++ni)
#pragma unroll
        for (int tt = 0; tt < 8; ++tt)
          X[ni][tt] = (unsigned)__shfl_xor((int)su32[ni][tt], 32);
#pragma unroll
      for (int c = 0; c < 4; ++c) {
        int ni = c >> 1, b4 = 4 * (c & 1);
        U8 w;
        w.u[0] = hib ? X[ni][b4 + 2] : su32[ni][b4 + 0];
        w.u[1] = hib ? X[ni][b4 + 3] : su32[ni][b4 + 1];
        w.u[2] = hib ? su32[ni][b4 + 2] : X[ni][b4 + 0];
        w.u[3] = hib ? su32[ni][b4 + 3] : X[ni][b4 + 1];
        pa[c] = w.s;
      }
#endif

      if (pref) { WAITV(8); } else { WAITV(0); }  // V(t) done; K(t+1) in flight

#pragma unroll
      for (int c = 0; c < 4; ++c) {
        zacc[0] = __builtin_amdgcn_mfma_f32_32x32x16_bf16(vf[0][c], pa[c], zacc[0], 0, 0, 0);
        zacc[1] = __builtin_amdgcn_mfma_f32_32x32x16_bf16(vf[1][c], pa[c], zacc[1], 0, 0, 0);
      }
    };

    int t = t0;
    while (true) {
      computeT(kfA, kfB, t);
      if (++t >= t1) break;
      computeT(kfB, kfA, t);
      if (++t >= t1) break;
    }
  }

  // ---- merge wave1 into wave0 (exact online-softmax combine) ----
  if (wvi == 1) {
#pragma unroll
    for (int i = 0; i < 16; ++i) {
      Zm[lane][i] = zacc[0][i];
      Zm[lane][16 + i] = zacc[1][i];
    }
    Ml[lane] = mrun;
    Ll[lane] = lrun;
  }
  __syncthreads();
  if (wvi == 0) {
    float m1 = Ml[lane], l1 = Ll[lane];
    float mn = fmaxf(mrun, m1);
    float a0 = fexp2(mrun - mn);
    float a1 = fexp2(m1 - mn);
    float lm = lrun * a0 + l1 * a1;
#pragma unroll
    for (int i = 0; i < 16; ++i) {
      zacc[0][i] = zacc[0][i] * a0 + Zm[lane][i] * a1;
      zacc[1][i] = zacc[1][i] * a0 + Zm[lane][16 + i] * a1;
    }

    // normalize + transpose Z^T -> Z via swizzled LDS, coalesced store
    const float rl = 1.0f / lm;
    const int W8[8] = {0, 1, 4, 5, 8, 9, 12, 13};
#pragma unroll
    for (int dj = 0; dj < 2; ++dj)
#pragma unroll
      for (int tt = 0; tt < 8; ++tt) {
        unsigned v = pack2(zacc[dj][2 * tt] * rl, zacc[dj][2 * tt + 1] * rl);
        int x = 16 * dj + (hib ? 2 : 0) + W8[tt];
        Zl[qln * 32 + (((x >> 2) ^ (qln & 7)) << 2) + (x & 3)] = v;
      }
    asm volatile("s_waitcnt lgkmcnt(0)" ::: "memory");
    __builtin_amdgcn_sched_barrier(0);
    const size_t base = ((size_t)bb * SEQ) * DM + h * DHD;
    int q2 = lane >> 1, hf = lane & 1;
#pragma unroll
    for (int u = 0; u < 4; ++u) {
      int sl = (hf * 4 + u) ^ (q2 & 7);
      U8 w;
      w.u = *(const uint4v*)&Zl[q2 * 32 + sl * 4];
      *(short8*)(Zb + base + (size_t)(q0 + q2) * DM + hf * 32 + u * 8) = w.s;
    }
  }
}

extern "C" void kernel_launch(void* const* d_in, const int* in_sizes, int n_in,
                              void* d_out, int out_size, void* d_ws, size_t ws_size,
                              hipStream_t stream) {
  (void)in_sizes; (void)n_in; (void)out_size; (void)ws_size;
  const float* x = (const float*)d_in[0];
  const float* pos = (const float*)d_in[1];
  const float* WQ = (const float*)d_in[2];
  const float* bQ = (const float*)d_in[3];
  const float* WK = (const float*)d_in[4];
  const float* bK = (const float*)d_in[5];
  const float* WV = (const float*)d_in[6];
  const float* bV = (const float*)d_in[7];
  const float* WO = (const float*)d_in[8];
  const float* bO = (const float*)d_in[9];
  float* out = (float*)d_out;

  bf16* ws = (bf16*)d_ws;
  size_t off = 0;
  bf16* aib = ws + off; off += (size_t)MROWS * DM;
  bf16* xb  = ws + off; off += (size_t)MROWS * DM;
  bf16* wqt = ws + off; off += (size_t)DM * DM;
  bf16* wkt = ws + off; off += (size_t)DM * DM;
  bf16* wvt = ws + off; off += (size_t)DM * DM;
  bf16* wot = ws + off; off += (size_t)DM * DM;
  bf16* FQ  = ws + off; off += (size_t)MROWS * DM;  // fragment-major [bh][g][kc]
  bf16* FK  = ws + off; off += (size_t)MROWS * DM;
  bf16* FV  = ws + off; off += (size_t)MROWS * DM;  // fragment-major [bh][dj][ks]
  bf16* Zb  = ws + off; off += (size_t)MROWS * DM;

  prep_inputs<<<(MROWS * DM / 4 + 255) / 256, 256, 0, stream>>>(x, pos, xb, aib);
  dim3 gq(1, 16, 16);
  transpose_w<<<gq, 256, 0, stream>>>(WQ, wqt, 1024, 64);
  transpose_w<<<gq, 256, 0, stream>>>(WK, wkt, 1024, 64);
  transpose_w<<<gq, 256, 0, stream>>>(WV, wvt, 1024, 64);
  dim3 go(16, 16, 1);
  transpose_w<<<go, 256, 0, stream>>>(WO, wot, 1024, 1024);
  qkv_gemm<<<768, 256, 0, stream>>>(aib, xb, wqt, wkt, wvt, bQ, bK, bV, FQ, FK, FV);
  flash_attn<<<2048, 128, 0, stream>>>(FQ, FK, FV, Zb);
  o_gemm64<<<512, 256, 0, stream>>>(Zb, wot, bO, out);
}